// Round 7
// baseline (419.494 us; speedup 1.0000x reference)
//
#include <hip/hip_runtime.h>
#include <math.h>

#define N_NODES 50000
#define N_EDGES 800000
#define HIDDEN  128
#define EDIM    32
#define NEG     0.2f

// ---------------------------------------------------------------------------
// ce1 = We1 @ ae1, ce2 = We2 @ ae2 (each [32])
// consts[0:32]=ce1, consts[32:64]=ce2
__global__ void prep_kernel(const float* __restrict__ We1, const float* __restrict__ ae1,
                            const float* __restrict__ We2, const float* __restrict__ ae2,
                            float* __restrict__ consts) {
    int t = threadIdx.x;
    if (t < 32) {
        float acc = 0.f;
        for (int k = 0; k < HIDDEN; k++) acc += We1[t * HIDDEN + k] * ae1[k];
        consts[t] = acc;
    } else if (t < 64) {
        int j = t - 32;
        float acc = 0.f;
        for (int k = 0; k < HIDDEN; k++) acc += We2[j * HIDDEN + k] * ae2[k];
        consts[32 + j] = acc;
    }
}

// ---------------------------------------------------------------------------
// CSR build step 1: in-degree histogram
__global__ void hist_kernel(const int* __restrict__ dst, int* __restrict__ count) {
    int e = blockIdx.x * blockDim.x + threadIdx.x;
    if (e < N_EDGES) atomicAdd(&count[dst[e]], 1);
}

// ---------------------------------------------------------------------------
// CSR build step 2: 3-phase parallel exclusive scan of count -> off_work
#define SCAN_BLOCKS ((N_NODES + 255) / 256)   // 196
// phase 1: per-block exclusive scan over a 256-chunk + block total
__global__ void scan1_kernel(const int* __restrict__ count,
                             int* __restrict__ off_work, int* __restrict__ blocksum) {
    __shared__ int sh[256];
    int t = threadIdx.x;
    int idx = blockIdx.x * 256 + t;
    int v = (idx < N_NODES) ? count[idx] : 0;
    sh[t] = v;
    __syncthreads();
    for (int off = 1; off < 256; off <<= 1) {
        int u = (t >= off) ? sh[t - off] : 0;
        __syncthreads();
        sh[t] += u;
        __syncthreads();
    }
    if (idx < N_NODES) off_work[idx] = sh[t] - v;          // exclusive in-block
    if (t == 255) blocksum[blockIdx.x] = sh[255];          // block total
}
// phase 2: exclusive scan of the 196 block totals (one block)
__global__ void scan2_kernel(int* __restrict__ blocksum, int* __restrict__ blockoff) {
    __shared__ int sh[256];
    int t = threadIdx.x;
    int v = (t < SCAN_BLOCKS) ? blocksum[t] : 0;
    sh[t] = v;
    __syncthreads();
    for (int off = 1; off < 256; off <<= 1) {
        int u = (t >= off) ? sh[t - off] : 0;
        __syncthreads();
        sh[t] += u;
        __syncthreads();
    }
    if (t < SCAN_BLOCKS) blockoff[t] = sh[t] - v;
}
// phase 3: add block offsets
__global__ void scan3_kernel(int* __restrict__ off_work, const int* __restrict__ blockoff) {
    int idx = blockIdx.x * 256 + threadIdx.x;
    if (idx < N_NODES) off_work[idx] += blockoff[blockIdx.x];
}

// CSR build step 4: scatter edges into dst-sorted order.
// After: off_work[i] == end offset of segment i; off_work[i-1] == start.
__global__ void scatter_kernel(const int* __restrict__ src, const int* __restrict__ dst,
                               int* __restrict__ off_work,
                               int* __restrict__ src_p, int* __restrict__ ipos) {
    int e = blockIdx.x * blockDim.x + threadIdx.x;
    if (e >= N_EDGES) return;
    int pos = atomicAdd(&off_work[dst[e]], 1);
    src_p[pos] = src[e];
    ipos[e] = pos;
}

// ---------------------------------------------------------------------------
// ONE coalesced pass over ea computing BOTH layers' edge scalars:
//   d1 = ea_e . ce1 ; d2 = ea_e . ce2
// scatter-store float2(d1,d2) into dst-sorted slot; accumulate sums of d1,d2
// into 64 padded partial slots (low-contention atomics).
__global__ void dotv_kernel(const float* __restrict__ ea, const float* __restrict__ consts,
                            const int* __restrict__ ipos,
                            float2* __restrict__ dotv_p, float* __restrict__ part) {
    __shared__ float cs[64];
    int t = threadIdx.x;
    if (t < 64) cs[t] = consts[t];
    __syncthreads();
    int e = blockIdx.x * blockDim.x + t;   // N_EDGES % 256 == 0
    const float4* ep = (const float4*)(ea + (size_t)e * EDIM);
    float d1 = 0.f, d2 = 0.f;
#pragma unroll
    for (int i = 0; i < 8; i++) {
        float4 v = ep[i];
        d1 += v.x * cs[4 * i] + v.y * cs[4 * i + 1] + v.z * cs[4 * i + 2] + v.w * cs[4 * i + 3];
        d2 += v.x * cs[32 + 4 * i] + v.y * cs[32 + 4 * i + 1] + v.z * cs[32 + 4 * i + 2] + v.w * cs[32 + 4 * i + 3];
    }
    dotv_p[ipos[e]] = make_float2(d1, d2);
    float s1 = d1, s2 = d2;
    for (int off = 32; off > 0; off >>= 1) {
        s1 += __shfl_down(s1, off, 64);
        s2 += __shfl_down(s2, off, 64);
    }
    if ((t & 63) == 0) {
        int slot = (blockIdx.x & 63) * 16;
        atomicAdd(&part[slot], s1);
        atomicAdd(&part[slot + 1], s2);
    }
}

// reduce the 64 padded partial slots -> sdv[0], sdv[1]  (single wave)
__global__ void reduce_sdv_kernel(const float* __restrict__ part, float* __restrict__ sdv) {
    int t = threadIdx.x;   // 64 threads
    float s1 = part[t * 16], s2 = part[t * 16 + 1];
    for (int off = 32; off > 0; off >>= 1) {
        s1 += __shfl_down(s1, off, 64);
        s2 += __shfl_down(s2, off, 64);
    }
    if (t == 0) { sdv[0] = s1; sdv[1] = s2; }
}

// ---------------------------------------------------------------------------
// h = x @ W, W column per thread (compiler may rematerialize), scalar (SGPR)
// x operands. 128 threads = 128 output cols. 8 independent row-accumulators
// for ILP; 16 rows/block -> 3125 blocks = 6250 waves (~6 waves/SIMD).
// fused: alpha[row] = h_row . a_s ; beta[row] = h_row . a_d
#define GR_PER_BLOCK 16
#define G_CHUNK 8
#define GEMM_BLOCKS (N_NODES / GR_PER_BLOCK)   // 3125
__global__ void __launch_bounds__(128)
gemm_node_kernel(const float* __restrict__ x, const float* __restrict__ W,
                 const float* __restrict__ a_s, const float* __restrict__ a_d,
                 float* __restrict__ h, float* __restrict__ alpha,
                 float* __restrict__ beta) {
    __shared__ float pa[2][G_CHUNK], pb[2][G_CHUNK];
    int col = threadIdx.x;             // 0..127
    float wreg[HIDDEN];
#pragma unroll
    for (int k = 0; k < HIDDEN; k++) wreg[k] = W[k * HIDDEN + col];  // coalesced
    float as_c = a_s[col], ad_c = a_d[col];
    int row0 = blockIdx.x * GR_PER_BLOCK;
    for (int r0 = row0; r0 < row0 + GR_PER_BLOCK; r0 += G_CHUNK) {
        float acc[G_CHUNK];
#pragma unroll
        for (int r = 0; r < G_CHUNK; r++) acc[r] = 0.f;
        const float* xr = x + (size_t)r0 * HIDDEN;
#pragma unroll
        for (int k = 0; k < HIDDEN; k++) {
#pragma unroll
            for (int r = 0; r < G_CHUNK; r++)
                acc[r] += xr[r * HIDDEN + k] * wreg[k];   // scalar x, VGPR w
        }
#pragma unroll
        for (int r = 0; r < G_CHUNK; r++)
            h[(size_t)(r0 + r) * HIDDEN + col] = acc[r];
        // alpha/beta reductions for the rows
#pragma unroll
        for (int r = 0; r < G_CHUNK; r++) {
            float va = acc[r] * as_c;
            float vb = acc[r] * ad_c;
            for (int off = 32; off > 0; off >>= 1) {
                va += __shfl_down(va, off, 64);
                vb += __shfl_down(vb, off, 64);
            }
            if ((col & 63) == 0) { pa[col >> 6][r] = va; pb[col >> 6][r] = vb; }
        }
        __syncthreads();
        if (col < G_CHUNK) {
            alpha[r0 + col] = pa[0][col] + pa[1][col];
            beta[r0 + col]  = pb[0][col] + pb[1][col];
        }
        __syncthreads();
    }
}

// ---------------------------------------------------------------------------
// Gather-aggregate: ONE WAVE PER NODE (4 nodes / 256-block, no barriers).
// Lane l owns channels 2l, 2l+1 (float2). Edge weights computed inline:
//   w = exp(leaky(alpha[src] + beta[i] + dotv)); broadcast via __shfl.
// Fused softmax denominator + self-loop + finalize.
// FINAL==0: write relu(v + b) to outp[N,128]   (conv1)
// FINAL==1: out[i] = relu(dot(v + b, Wl) + bl) (conv2 + final linear)
template<int LAYER, int FINAL>
__global__ void __launch_bounds__(256)
agg_kernel(const int* __restrict__ off_work,
           const int* __restrict__ src_p,
           const float2* __restrict__ dotv_p,
           const float* __restrict__ h,
           const float* __restrict__ alpha, const float* __restrict__ beta,
           const float* __restrict__ b, const float* __restrict__ sdv,
           const float* __restrict__ Wl, const float* __restrict__ bl,
           float* __restrict__ outp) {
    int t = threadIdx.x;
    int l = t & 63;
    int i = blockIdx.x * 4 + (t >> 6);       // node id (grid covers N exactly)
    int start = (i == 0) ? 0 : off_work[i - 1];
    int end   = off_work[i];
    float beta_i = beta[i];
    float2 acc = make_float2(0.f, 0.f);
    float wsum = 0.f;
    for (int cb = start; cb < end; cb += 64) {
        int n = min(64, end - cb);
        int sp = 0; float wt = 0.f;
        if (l < n) {
            sp = src_p[cb + l];
            float2 dv = dotv_p[cb + l];
            float lg = alpha[sp] + beta_i + (LAYER == 0 ? dv.x : dv.y);
            lg = lg > 0.f ? lg : NEG * lg;
            wt = expf(lg);
        }
        for (int j = 0; j < n; j++) {
            float w = __shfl(wt, j, 64);
            int   sj = __shfl(sp, j, 64);
            float2 hv = ((const float2*)(h + (size_t)sj * HIDDEN))[l];
            acc.x += w * hv.x;
            acc.y += w * hv.y;
            wsum  += w;
        }
    }
    // self-loop edge (edge feature = mean over edges of dotv)
    float selfc = sdv[LAYER] * (1.f / (float)N_EDGES);
    float lg = alpha[i] + beta_i + selfc;
    lg = lg > 0.f ? lg : NEG * lg;
    float exi = expf(lg);
    float denom = wsum + exi + 1e-16f;
    float2 hv = ((const float2*)(h + (size_t)i * HIDDEN))[l];
    float2 bb = ((const float2*)b)[l];
    float2 v;
    v.x = (acc.x + exi * hv.x) / denom + bb.x;
    v.y = (acc.y + exi * hv.y) / denom + bb.y;
    if (FINAL == 0) {
        ((float2*)(outp + (size_t)i * HIDDEN))[l] =
            make_float2(fmaxf(v.x, 0.f), fmaxf(v.y, 0.f));
    } else {
        float2 wl = ((const float2*)Wl)[l];
        float contrib = v.x * wl.x + v.y * wl.y;
        for (int off = 32; off > 0; off >>= 1) contrib += __shfl_down(contrib, off, 64);
        if (l == 0) outp[i] = fmaxf(contrib + bl[0], 0.f);
    }
}

// ---------------------------------------------------------------------------
extern "C" void kernel_launch(void* const* d_in, const int* in_sizes, int n_in,
                              void* d_out, int out_size, void* d_ws, size_t ws_size,
                              hipStream_t stream) {
    const float* x   = (const float*)d_in[0];
    const int*   src = (const int*)  d_in[1];
    const int*   dst = (const int*)  d_in[2];
    const float* ea  = (const float*)d_in[3];
    const float* W1  = (const float*)d_in[4];
    const float* We1 = (const float*)d_in[5];
    const float* as1 = (const float*)d_in[6];
    const float* ad1 = (const float*)d_in[7];
    const float* ae1 = (const float*)d_in[8];
    const float* b1  = (const float*)d_in[9];
    const float* W2  = (const float*)d_in[10];
    const float* We2 = (const float*)d_in[11];
    const float* as2 = (const float*)d_in[12];
    const float* ad2 = (const float*)d_in[13];
    const float* ae2 = (const float*)d_in[14];
    const float* b2  = (const float*)d_in[15];
    const float* Wl  = (const float*)d_in[16];
    const float* bl  = (const float*)d_in[17];
    float* out = (float*)d_out;

    float* ws      = (float*)d_ws;
    float* A       = ws;                           // [N*128]  h1, then h2
    float* B       = A + (size_t)N_NODES * HIDDEN; // [N*128]  out1 (conv1 result)
    float* alpha   = B + (size_t)N_NODES * HIDDEN; // [N]
    float* beta    = alpha + N_NODES;              // [N]
    float2* dotv_p = (float2*)(beta + N_NODES);    // [E] (d1,d2) dst-sorted
    float* consts  = (float*)(dotv_p + N_EDGES);   // [64] ce1, ce2
    float* part    = consts + 64;                  // [64*16] padded partials
    float* sdv     = part + 64 * 16;               // [2]
    int* count     = (int*)(sdv + 2);              // [N]
    int* off_work  = count + N_NODES;              // [N]
    int* blocksum  = off_work + N_NODES;           // [SCAN_BLOCKS]
    int* blockoff  = blocksum + SCAN_BLOCKS;       // [SCAN_BLOCKS]
    int* src_p     = blockoff + SCAN_BLOCKS;       // [E] dst-sorted src ids
    int* ipos      = src_p + N_EDGES;              // [E] edge -> sorted slot

    const int EB = (N_EDGES + 255) / 256;

    // ---- prep: edge-logit constants, CSR build, single ea pass ----
    hipMemsetAsync(count, 0, N_NODES * sizeof(int), stream);
    hipMemsetAsync(part, 0, 64 * 16 * sizeof(float), stream);
    prep_kernel<<<1, 64, 0, stream>>>(We1, ae1, We2, ae2, consts);
    hist_kernel<<<EB, 256, 0, stream>>>(dst, count);
    scan1_kernel<<<SCAN_BLOCKS, 256, 0, stream>>>(count, off_work, blocksum);
    scan2_kernel<<<1, 256, 0, stream>>>(blocksum, blockoff);
    scan3_kernel<<<SCAN_BLOCKS, 256, 0, stream>>>(off_work, blockoff);
    scatter_kernel<<<EB, 256, 0, stream>>>(src, dst, off_work, src_p, ipos);
    dotv_kernel<<<EB, 256, 0, stream>>>(ea, consts, ipos, dotv_p, part);
    reduce_sdv_kernel<<<1, 64, 0, stream>>>(part, sdv);

    // ---- conv1 ----
    gemm_node_kernel<<<GEMM_BLOCKS, 128, 0, stream>>>(x, W1, as1, ad1, A, alpha, beta);
    agg_kernel<0, 0><<<N_NODES / 4, 256, 0, stream>>>(off_work, src_p, dotv_p, A, alpha, beta,
                                                      b1, sdv, nullptr, nullptr, B);

    // ---- conv2 (+ final linear fused) ----
    gemm_node_kernel<<<GEMM_BLOCKS, 128, 0, stream>>>(B, W2, as2, ad2, A, alpha, beta);
    agg_kernel<1, 1><<<N_NODES / 4, 256, 0, stream>>>(off_work, src_p, dotv_p, A, alpha, beta,
                                                      b2, sdv, Wl, bl, out);
}

// Round 8
// 328.304 us; speedup vs baseline: 1.2778x; 1.2778x over previous
//
#include <hip/hip_runtime.h>
#include <math.h>

#define N_NODES 50000
#define N_EDGES 800000
#define HIDDEN  128
#define EDIM    32
#define NEG     0.2f

typedef __attribute__((ext_vector_type(8))) short bshort8;
typedef __attribute__((ext_vector_type(4))) float f32x4;

__device__ __forceinline__ unsigned short f2bf(float f) {
    unsigned u = __builtin_bit_cast(unsigned, f);
    return (unsigned short)((u + 0x7FFFu + ((u >> 16) & 1u)) >> 16);
}
__device__ __forceinline__ float bf2f(unsigned short b) {
    unsigned u = ((unsigned)b) << 16;
    return __builtin_bit_cast(float, u);
}

// ---------------------------------------------------------------------------
// ce1 = We1 @ ae1, ce2 = We2 @ ae2 (each [32])
__global__ void prep_kernel(const float* __restrict__ We1, const float* __restrict__ ae1,
                            const float* __restrict__ We2, const float* __restrict__ ae2,
                            float* __restrict__ consts) {
    int t = threadIdx.x;
    if (t < 32) {
        float acc = 0.f;
        for (int k = 0; k < HIDDEN; k++) acc += We1[t * HIDDEN + k] * ae1[k];
        consts[t] = acc;
    } else if (t < 64) {
        int j = t - 32;
        float acc = 0.f;
        for (int k = 0; k < HIDDEN; k++) acc += We2[j * HIDDEN + k] * ae2[k];
        consts[32 + j] = acc;
    }
}

// ---------------------------------------------------------------------------
// Pack W (128x128 row-major, [k][col]) into MFMA B-fragment order, bf16 split.
// frag index: (((ct*4 + kc)*64 + lane)*8 + e)  with k = kc*32+(lane>>4)*8+e,
// col = ct*16+(lane&15).  Same k-bijection is used for the A pack in the gemm,
// so any HW-internal k permutation cancels in the contraction.
__global__ void pack_w_kernel(const float* __restrict__ W,
                              unsigned short* __restrict__ whp,
                              unsigned short* __restrict__ wlp) {
    int idx = blockIdx.x * 256 + threadIdx.x;   // 16384 total
    int e  = idx & 7;
    int l  = (idx >> 3) & 63;
    int kc = (idx >> 9) & 3;
    int ct = (idx >> 11);
    int k   = kc * 32 + ((l >> 4) << 3) + e;
    int col = ct * 16 + (l & 15);
    float w = W[k * HIDDEN + col];
    unsigned short hb = f2bf(w);
    whp[idx] = hb;
    wlp[idx] = f2bf(w - bf2f(hb));
}

// ---------------------------------------------------------------------------
// CSR build step 1: in-degree histogram
__global__ void hist_kernel(const int* __restrict__ dst, int* __restrict__ count) {
    int e = blockIdx.x * blockDim.x + threadIdx.x;
    if (e < N_EDGES) atomicAdd(&count[dst[e]], 1);
}

// CSR build step 2: 3-phase parallel exclusive scan of count -> off_work
#define SCAN_BLOCKS ((N_NODES + 255) / 256)   // 196
__global__ void scan1_kernel(const int* __restrict__ count,
                             int* __restrict__ off_work, int* __restrict__ blocksum) {
    __shared__ int sh[256];
    int t = threadIdx.x;
    int idx = blockIdx.x * 256 + t;
    int v = (idx < N_NODES) ? count[idx] : 0;
    sh[t] = v;
    __syncthreads();
    for (int off = 1; off < 256; off <<= 1) {
        int u = (t >= off) ? sh[t - off] : 0;
        __syncthreads();
        sh[t] += u;
        __syncthreads();
    }
    if (idx < N_NODES) off_work[idx] = sh[t] - v;
    if (t == 255) blocksum[blockIdx.x] = sh[255];
}
__global__ void scan2_kernel(int* __restrict__ blocksum, int* __restrict__ blockoff) {
    __shared__ int sh[256];
    int t = threadIdx.x;
    int v = (t < SCAN_BLOCKS) ? blocksum[t] : 0;
    sh[t] = v;
    __syncthreads();
    for (int off = 1; off < 256; off <<= 1) {
        int u = (t >= off) ? sh[t - off] : 0;
        __syncthreads();
        sh[t] += u;
        __syncthreads();
    }
    if (t < SCAN_BLOCKS) blockoff[t] = sh[t] - v;
}
__global__ void scan3_kernel(int* __restrict__ off_work, const int* __restrict__ blockoff) {
    int idx = blockIdx.x * 256 + threadIdx.x;
    if (idx < N_NODES) off_work[idx] += blockoff[blockIdx.x];
}

// CSR build step 4: scatter edges into dst-sorted order.
__global__ void scatter_kernel(const int* __restrict__ src, const int* __restrict__ dst,
                               int* __restrict__ off_work,
                               int* __restrict__ src_p, int* __restrict__ ipos) {
    int e = blockIdx.x * blockDim.x + threadIdx.x;
    if (e >= N_EDGES) return;
    int pos = atomicAdd(&off_work[dst[e]], 1);
    src_p[pos] = src[e];
    ipos[e] = pos;
}

// ---------------------------------------------------------------------------
// ONE coalesced pass over ea computing BOTH layers' edge scalars.
__global__ void dotv_kernel(const float* __restrict__ ea, const float* __restrict__ consts,
                            const int* __restrict__ ipos,
                            float2* __restrict__ dotv_p, float* __restrict__ part) {
    __shared__ float cs[64];
    int t = threadIdx.x;
    if (t < 64) cs[t] = consts[t];
    __syncthreads();
    int e = blockIdx.x * blockDim.x + t;
    const float4* ep = (const float4*)(ea + (size_t)e * EDIM);
    float d1 = 0.f, d2 = 0.f;
#pragma unroll
    for (int i = 0; i < 8; i++) {
        float4 v = ep[i];
        d1 += v.x * cs[4 * i] + v.y * cs[4 * i + 1] + v.z * cs[4 * i + 2] + v.w * cs[4 * i + 3];
        d2 += v.x * cs[32 + 4 * i] + v.y * cs[32 + 4 * i + 1] + v.z * cs[32 + 4 * i + 2] + v.w * cs[32 + 4 * i + 3];
    }
    dotv_p[ipos[e]] = make_float2(d1, d2);
    float s1 = d1, s2 = d2;
    for (int off = 32; off > 0; off >>= 1) {
        s1 += __shfl_down(s1, off, 64);
        s2 += __shfl_down(s2, off, 64);
    }
    if ((t & 63) == 0) {
        int slot = (blockIdx.x & 63) * 16;
        atomicAdd(&part[slot], s1);
        atomicAdd(&part[slot + 1], s2);
    }
}

__global__ void reduce_sdv_kernel(const float* __restrict__ part, float* __restrict__ sdv) {
    int t = threadIdx.x;   // 64 threads
    float s1 = part[t * 16], s2 = part[t * 16 + 1];
    for (int off = 32; off > 0; off >>= 1) {
        s1 += __shfl_down(s1, off, 64);
        s2 += __shfl_down(s2, off, 64);
    }
    if (t == 0) { sdv[0] = s1; sdv[1] = s2; }
}

// ---------------------------------------------------------------------------
// MFMA gemm: h = x @ W via bf16 split (xh+xl)@(Wh+Wl), dropping xl@Wl.
// One wave per 16-row tile; 4 waves/block. 50000 = 16*3125 tiles exactly.
// A lane mapping (assumed, cancels if HW permutes k identically for A and B):
//   A[row=l&15][k = kc*32 + (l>>4)*8 + e]
// C/D (HW-verified): col = l&15, row = (l>>4)*4 + reg.
// fused: alpha[row] = h_row . a_s ; beta[row] = h_row . a_d
#define TILES_M (N_NODES / 16)                // 3125
#define GEMM_BLOCKS ((TILES_M + 3) / 4)       // 782
__global__ void __launch_bounds__(256)
gemm_mfma_kernel(const float* __restrict__ x,
                 const unsigned short* __restrict__ wh,
                 const unsigned short* __restrict__ wl,
                 const float* __restrict__ a_s, const float* __restrict__ a_d,
                 float* __restrict__ h, float* __restrict__ alpha,
                 float* __restrict__ beta) {
    int tile = blockIdx.x * 4 + (threadIdx.x >> 6);
    if (tile >= TILES_M) return;
    int l    = threadIdx.x & 63;
    int row0 = tile * 16;
    int arow = l & 15;            // A row / D col
    int kg   = l >> 4;            // k-group / D row-group
    // ---- load + split A fragments (8 consecutive floats per kc) ----
    bshort8 ah[4], al[4];
    const float* xr = x + (size_t)(row0 + arow) * HIDDEN + (kg << 3);
#pragma unroll
    for (int kc = 0; kc < 4; kc++) {
        float4 f0 = *(const float4*)(xr + kc * 32);
        float4 f1 = *(const float4*)(xr + kc * 32 + 4);
        float fv[8] = {f0.x, f0.y, f0.z, f0.w, f1.x, f1.y, f1.z, f1.w};
#pragma unroll
        for (int e = 0; e < 8; e++) {
            unsigned short hb = f2bf(fv[e]);
            ah[kc][e] = (short)hb;
            al[kc][e] = (short)f2bf(fv[e] - bf2f(hb));
        }
    }
    // ---- per col-tile: 4 kc x 3 mfma, then store + alpha/beta partials ----
    float pal[4] = {0.f, 0.f, 0.f, 0.f};
    float pbe[4] = {0.f, 0.f, 0.f, 0.f};
#pragma unroll
    for (int ct = 0; ct < 8; ct++) {
        f32x4 acc = {0.f, 0.f, 0.f, 0.f};
#pragma unroll
        for (int kc = 0; kc < 4; kc++) {
            int fo = (((ct * 4 + kc) * 64) + l) << 3;
            bshort8 bh = *(const bshort8*)(wh + fo);
            bshort8 bl = *(const bshort8*)(wl + fo);
            acc = __builtin_amdgcn_mfma_f32_16x16x32_bf16(ah[kc], bh, acc, 0, 0, 0);
            acc = __builtin_amdgcn_mfma_f32_16x16x32_bf16(al[kc], bh, acc, 0, 0, 0);
            acc = __builtin_amdgcn_mfma_f32_16x16x32_bf16(ah[kc], bl, acc, 0, 0, 0);
        }
        int col = ct * 16 + arow;
        float a_sc = a_s[col], a_dc = a_d[col];
#pragma unroll
        for (int j = 0; j < 4; j++) {
            h[(size_t)(row0 + kg * 4 + j) * HIDDEN + col] = acc[j];
            pal[j] += acc[j] * a_sc;
            pbe[j] += acc[j] * a_dc;
        }
    }
    // reduce partials across the 16 lanes of each kg group (cols)
#pragma unroll
    for (int m = 1; m < 16; m <<= 1) {
#pragma unroll
        for (int j = 0; j < 4; j++) {
            pal[j] += __shfl_xor(pal[j], m, 64);
            pbe[j] += __shfl_xor(pbe[j], m, 64);
        }
    }
    if (arow == 0) {
#pragma unroll
        for (int j = 0; j < 4; j++) {
            alpha[row0 + kg * 4 + j] = pal[j];
            beta[row0 + kg * 4 + j]  = pbe[j];
        }
    }
}

// ---------------------------------------------------------------------------
// Gather-aggregate: ONE WAVE PER NODE (4 nodes / 256-block, no barriers).
template<int LAYER, int FINAL>
__global__ void __launch_bounds__(256)
agg_kernel(const int* __restrict__ off_work,
           const int* __restrict__ src_p,
           const float2* __restrict__ dotv_p,
           const float* __restrict__ h,
           const float* __restrict__ alpha, const float* __restrict__ beta,
           const float* __restrict__ b, const float* __restrict__ sdv,
           const float* __restrict__ Wl, const float* __restrict__ bl,
           float* __restrict__ outp) {
    int t = threadIdx.x;
    int l = t & 63;
    int i = blockIdx.x * 4 + (t >> 6);
    int start = (i == 0) ? 0 : off_work[i - 1];
    int end   = off_work[i];
    float beta_i = beta[i];
    float2 acc = make_float2(0.f, 0.f);
    float wsum = 0.f;
    for (int cb = start; cb < end; cb += 64) {
        int n = min(64, end - cb);
        int sp = 0; float wt = 0.f;
        if (l < n) {
            sp = src_p[cb + l];
            float2 dv = dotv_p[cb + l];
            float lg = alpha[sp] + beta_i + (LAYER == 0 ? dv.x : dv.y);
            lg = lg > 0.f ? lg : NEG * lg;
            wt = expf(lg);
        }
        for (int j = 0; j < n; j++) {
            float w = __shfl(wt, j, 64);
            int   sj = __shfl(sp, j, 64);
            float2 hv = ((const float2*)(h + (size_t)sj * HIDDEN))[l];
            acc.x += w * hv.x;
            acc.y += w * hv.y;
            wsum  += w;
        }
    }
    float selfc = sdv[LAYER] * (1.f / (float)N_EDGES);
    float lg = alpha[i] + beta_i + selfc;
    lg = lg > 0.f ? lg : NEG * lg;
    float exi = expf(lg);
    float denom = wsum + exi + 1e-16f;
    float2 hv = ((const float2*)(h + (size_t)i * HIDDEN))[l];
    float2 bb = ((const float2*)b)[l];
    float2 v;
    v.x = (acc.x + exi * hv.x) / denom + bb.x;
    v.y = (acc.y + exi * hv.y) / denom + bb.y;
    if (FINAL == 0) {
        ((float2*)(outp + (size_t)i * HIDDEN))[l] =
            make_float2(fmaxf(v.x, 0.f), fmaxf(v.y, 0.f));
    } else {
        float2 wl = ((const float2*)Wl)[l];
        float contrib = v.x * wl.x + v.y * wl.y;
        for (int off = 32; off > 0; off >>= 1) contrib += __shfl_down(contrib, off, 64);
        if (l == 0) outp[i] = fmaxf(contrib + bl[0], 0.f);
    }
}

// ---------------------------------------------------------------------------
extern "C" void kernel_launch(void* const* d_in, const int* in_sizes, int n_in,
                              void* d_out, int out_size, void* d_ws, size_t ws_size,
                              hipStream_t stream) {
    const float* x   = (const float*)d_in[0];
    const int*   src = (const int*)  d_in[1];
    const int*   dst = (const int*)  d_in[2];
    const float* ea  = (const float*)d_in[3];
    const float* W1  = (const float*)d_in[4];
    const float* We1 = (const float*)d_in[5];
    const float* as1 = (const float*)d_in[6];
    const float* ad1 = (const float*)d_in[7];
    const float* ae1 = (const float*)d_in[8];
    const float* b1  = (const float*)d_in[9];
    const float* W2  = (const float*)d_in[10];
    const float* We2 = (const float*)d_in[11];
    const float* as2 = (const float*)d_in[12];
    const float* ad2 = (const float*)d_in[13];
    const float* ae2 = (const float*)d_in[14];
    const float* b2  = (const float*)d_in[15];
    const float* Wl  = (const float*)d_in[16];
    const float* bl  = (const float*)d_in[17];
    float* out = (float*)d_out;

    float* ws      = (float*)d_ws;
    float* A       = ws;                           // [N*128]  h1, then h2
    float* B       = A + (size_t)N_NODES * HIDDEN; // [N*128]  out1 (conv1 result)
    // packed W fragments (bf16 split), 16B-aligned (offset 12.8M floats)
    unsigned short* whp1 = (unsigned short*)(B + (size_t)N_NODES * HIDDEN);
    unsigned short* wlp1 = whp1 + 16384;
    unsigned short* whp2 = wlp1 + 16384;
    unsigned short* wlp2 = whp2 + 16384;           // ends at +32768 floats
    float* alpha   = (float*)(wlp2 + 16384);       // [N]
    float* beta    = alpha + N_NODES;              // [N]
    float2* dotv_p = (float2*)(beta + N_NODES);    // [E] (d1,d2) dst-sorted
    float* consts  = (float*)(dotv_p + N_EDGES);   // [64] ce1, ce2
    float* part    = consts + 64;                  // [64*16] padded partials
    float* sdv     = part + 64 * 16;               // [2]
    int* count     = (int*)(sdv + 2);              // [N]
    int* off_work  = count + N_NODES;              // [N]
    int* blocksum  = off_work + N_NODES;           // [SCAN_BLOCKS]
    int* blockoff  = blocksum + SCAN_BLOCKS;       // [SCAN_BLOCKS]
    int* src_p     = blockoff + SCAN_BLOCKS;       // [E] dst-sorted src ids
    int* ipos      = src_p + N_EDGES;              // [E] edge -> sorted slot

    const int EB = (N_EDGES + 255) / 256;

    // ---- prep: edge-logit constants, W frag pack, CSR build, ea pass ----
    hipMemsetAsync(count, 0, N_NODES * sizeof(int), stream);
    hipMemsetAsync(part, 0, 64 * 16 * sizeof(float), stream);
    prep_kernel<<<1, 64, 0, stream>>>(We1, ae1, We2, ae2, consts);
    pack_w_kernel<<<64, 256, 0, stream>>>(W1, whp1, wlp1);
    pack_w_kernel<<<64, 256, 0, stream>>>(W2, whp2, wlp2);
    hist_kernel<<<EB, 256, 0, stream>>>(dst, count);
    scan1_kernel<<<SCAN_BLOCKS, 256, 0, stream>>>(count, off_work, blocksum);
    scan2_kernel<<<1, 256, 0, stream>>>(blocksum, blockoff);
    scan3_kernel<<<SCAN_BLOCKS, 256, 0, stream>>>(off_work, blockoff);
    scatter_kernel<<<EB, 256, 0, stream>>>(src, dst, off_work, src_p, ipos);
    dotv_kernel<<<EB, 256, 0, stream>>>(ea, consts, ipos, dotv_p, part);
    reduce_sdv_kernel<<<1, 64, 0, stream>>>(part, sdv);

    // ---- conv1 ----
    gemm_mfma_kernel<<<GEMM_BLOCKS, 256, 0, stream>>>(x, whp1, wlp1, as1, ad1,
                                                      A, alpha, beta);
    agg_kernel<0, 0><<<N_NODES / 4, 256, 0, stream>>>(off_work, src_p, dotv_p, A, alpha, beta,
                                                      b1, sdv, nullptr, nullptr, B);

    // ---- conv2 (+ final linear fused) ----
    gemm_mfma_kernel<<<GEMM_BLOCKS, 256, 0, stream>>>(B, whp2, wlp2, as2, ad2,
                                                      A, alpha, beta);
    agg_kernel<1, 1><<<N_NODES / 4, 256, 0, stream>>>(off_work, src_p, dotv_p, A, alpha, beta,
                                                      b2, sdv, Wl, bl, out);
}